// Round 16
// baseline (203.057 us; speedup 1.0000x reference)
//
#include <hip/hip_runtime.h>
#include <hip/hip_bf16.h>
#include <math.h>

typedef short bf16x8 __attribute__((ext_vector_type(8)));
typedef float f32x4 __attribute__((ext_vector_type(4)));

#define QKSCALE_L2E 0.25505402227437564f  // 32^-0.5 * log2(e)
#define LOG2E 1.4426950408889634f

__device__ __forceinline__ unsigned short f2bf(float f) {
  __hip_bfloat16 h = __float2bfloat16(f);
  return *reinterpret_cast<unsigned short*>(&h);
}
__device__ __forceinline__ float bf2f(unsigned short h) {
  return __uint_as_float(((unsigned int)h) << 16);
}
__device__ __forceinline__ unsigned int pk2(float lo, float hi) {
  __hip_bfloat162 h = __float22bfloat162_rn(make_float2(lo, hi));
  return *reinterpret_cast<unsigned int*>(&h);
}
__device__ __forceinline__ bf16x8 pack8(const float* g) {
  union { unsigned int u[4]; bf16x8 v; } t;
  t.u[0] = pk2(g[0], g[1]); t.u[1] = pk2(g[2], g[3]);
  t.u[2] = pk2(g[4], g[5]); t.u[3] = pk2(g[6], g[7]);
  return t.v;
}

// XOR-swizzled LDS helpers (bf16 tiles, swizzle in 16B units on row bits)
__device__ __forceinline__ bf16x8 ldsv(const unsigned short* base, int row, int strideHalfs, int kHalf, int swzMask) {
  int byte = row * strideHalfs * 2 + kHalf * 2;
  byte ^= (row & swzMask) << 4;
  return *(const bf16x8*)((const char*)base + byte);
}
__device__ __forceinline__ void ldss(unsigned short* base, int row, int strideHalfs, int col, int swzMask, unsigned short v) {
  int byte = row * strideHalfs * 2 + col * 2;
  byte ^= (row & swzMask) << 4;
  *(unsigned short*)((char*)base + byte) = v;
}
__device__ __forceinline__ void ldst64(unsigned short* base, int row, int strideHalfs, int colHalf, int swzMask, unsigned int lo, unsigned int hi) {
  int byte = row * strideHalfs * 2 + colHalf * 2;
  byte ^= (row & swzMask) << 4;
  uint2 val; val.x = lo; val.y = hi;
  *(uint2*)((char*)base + byte) = val;
}
// q/k/q2 [64][32-half] tiles: bank-bit-4 swizzle -> 2-way (free) b32 stores,
// optimal-b128 reads. byte ^= ((row>>2)&1)<<6 is a bijection on the 4KB tile.
__device__ __forceinline__ void ldst32q(unsigned short* base, int row, int colHalf, unsigned int v) {
  int byte = row * 64 + colHalf * 2;
  byte ^= ((row >> 2) & 1) << 6;
  *(unsigned int*)((char*)base + byte) = v;
}
__device__ __forceinline__ bf16x8 ldsvq(const unsigned short* base, int row, int kHalf) {
  int byte = row * 64 + kHalf * 2;
  byte ^= ((row >> 2) & 1) << 6;
  return *(const bf16x8*)((const char*)base + byte);
}

// ---------------- prep: fragment-ordered bf16 weights ----------------
__global__ void prep_kernel(
    const float* __restrict__ qkv1_w, const float* __restrict__ qkv1_b,
    const float* __restrict__ proj_w, const float* __restrict__ fc1_w,
    const float* __restrict__ fc2_w,  const float* __restrict__ rpb,
    unsigned short* __restrict__ Wqkvf, unsigned short* __restrict__ Wprojf,
    unsigned short* __restrict__ Wfc1f, unsigned short* __restrict__ Wfc2f,
    float* __restrict__ bqkv, float* __restrict__ biasmat)
{
  int i = blockIdx.x * 256 + threadIdx.x;
  if (i < 65536) {  // Wqkvf: frag = ((comp*4+h)*2+sub16)*4+kk
    int j = i & 7, lane = (i >> 3) & 63, kk = (i >> 9) & 3;
    int sub16 = (i >> 11) & 1, h = (i >> 12) & 3, comp = i >> 14;
    int row = comp * 128 + h * 32 + sub16 * 16 + (lane & 15);
    int col = kk * 32 + (lane >> 4) * 8 + j;
    float sc = (comp == 0 || comp == 3) ? QKSCALE_L2E : 1.f;
    Wqkvf[i] = f2bf(qkv1_w[row * 128 + col] * sc);
  }
  int o = i - 65536;
  if (o >= 0 && o < 16384) {  // Wprojf: frag = nf*4+kk ; k-col pi1-permuted
    int j = o & 7, lane = (o >> 3) & 63, kk = (o >> 9) & 3, nf = o >> 11;
    int row = nf * 16 + (lane & 15);
    int cp = kk * 32 + (lane >> 4) * 8 + j;
    int H = cp >> 5, q = cp & 31, a = q >> 1, b = q & 1;
    Wprojf[o] = f2bf(proj_w[row * 128 + H * 32 + 16 * b + a]);
  }
  o -= 16384;
  if (o >= 0 && o < 65536) {  // Wfc1f: frag = n16*4+kk ; k-col pi-permuted
    int j = o & 7, lane = (o >> 3) & 63, kk = (o >> 9) & 3, n16 = o >> 11;
    int row = n16 * 16 + (lane & 15);
    int cp = kk * 32 + (lane >> 4) * 8 + j;
    Wfc1f[o] = f2bf(fc1_w[row * 128 + 16 * (cp & 7) + (cp >> 3)]);
  }
  o -= 65536;
  if (o >= 0 && o < 65536) {  // Wfc2f: frag = n8*16+kk ; k-col matches 8-wave hbuf pack
    int j = o & 7, lane = (o >> 3) & 63, kk = (o >> 9) & 15, n8 = o >> 13;
    int row = n8 * 16 + (lane & 15);
    int m = kk * 32 + (lane >> 4) * 8 + j;
    int src = (m >> 6) * 64 + 16 * (m & 3) + ((m >> 2) & 15);
    Wfc2f[o] = f2bf(fc2_w[row * 512 + src]);
  }
  o -= 65536;
  if (o >= 0 && o < 512) {
    int comp = o >> 7;
    bqkv[o] = qkv1_b[o] * ((comp == 0 || comp == 3) ? QKSCALE_L2E : 1.f);
  }
  o -= 512;
  if (o >= 0 && o < 16384) {  // biasmat[h][n][m], scaled by log2(e)
    int hh = o >> 12, n = (o >> 6) & 63, m = o & 63;
    int di = (n >> 3) - (m >> 3) + 7, dj = (n & 7) - (m & 7) + 7;
    biasmat[o] = rpb[(di * 15 + dj) * 4 + hh] * LOG2E;
  }
}

// ---------------- LN1 -> fragment-ordered bf16 tokens (xg) + raw-x bf16 copy (xb) ----------------
__global__ void __launch_bounds__(256) ln1_kernel(
    const float* __restrict__ x_in, const float* __restrict__ d_in_,
    const float* __restrict__ n1w, const float* __restrict__ n1b,
    unsigned short* __restrict__ xg, unsigned short* __restrict__ xb)
{
  const int s = blockIdx.x >> 10;
  const int row0 = (blockIdx.x & 1023) * 64;
  const int t = threadIdx.x >> 2, q4 = threadIdx.x & 3;
  const int grow = row0 + t;
  const int b2 = grow >> 14, rem = grow & 16383;
  const int gy = rem >> 7, gx = rem & 127;
  const int win = b2 * 256 + (gy >> 3) * 16 + (gx >> 3);
  const int tok = (gy & 7) * 8 + (gx & 7);
  const float* src = (s ? d_in_ : x_in) + (size_t)grow * 128 + q4 * 32;
  float v[32];
  float sum = 0.f, ss = 0.f;
#pragma unroll
  for (int i = 0; i < 8; ++i) {
    float4 f = ((const float4*)src)[i];
    v[i * 4 + 0] = f.x; v[i * 4 + 1] = f.y; v[i * 4 + 2] = f.z; v[i * 4 + 3] = f.w;
    sum += f.x + f.y + f.z + f.w;
    ss += f.x * f.x + f.y * f.y + f.z * f.z + f.w * f.w;
  }
  sum += __shfl_xor(sum, 1); sum += __shfl_xor(sum, 2);
  ss  += __shfl_xor(ss, 1);  ss  += __shfl_xor(ss, 2);
  float mean = sum * (1.f / 128.f);
  float var = ss * (1.f / 128.f) - mean * mean;
  float rs = rsqrtf(var + 1e-5f);
  // raw-x bf16 copy, linear row order (proj's residual base)
  unsigned short* xbd = xb + ((size_t)s * 65536 + grow) * 128 + q4 * 32;
#pragma unroll
  for (int i = 0; i < 4; ++i) *(bf16x8*)(xbd + i * 8) = pack8(v + i * 8);
  unsigned short* base = xg + ((size_t)(s * 1024 + win)) * 8192
                         + ((tok >> 4) * 4 + q4) * 512 + (tok & 15) * 8;
#pragma unroll
  for (int i = 0; i < 4; ++i) {
    float g[8];
#pragma unroll
    for (int jj = 0; jj < 8; ++jj) {
      int c = q4 * 32 + i * 8 + jj;
      g[jj] = (v[i * 8 + jj] - mean) * rs * n1w[c] + n1b[c];
    }
    *(bf16x8*)(base + i * 128) = pack8(g);
  }
}

// ---------------- attention: 1 block = (window, head), both streams ----------------
// Head-major grid; deferred alias barrier; 2-way-store swizzle; no-max softmax
// (scores std ~0.07 in exp2 domain -> max subtraction is mathematically inert);
// s_setprio around MFMA clusters (independent blocks at different phases).
__global__ void __launch_bounds__(256, 4) attn_kernel(
    const unsigned short* __restrict__ xg,
    const unsigned short* __restrict__ Wqkvf, const float* __restrict__ bqkv,
    const float* __restrict__ biasmat,
    unsigned short* __restrict__ aout)
{
  __shared__ unsigned short smem[2][10240];

  const int tid = threadIdx.x, wid = tid >> 6, lane = tid & 63;
  const int l4 = lane >> 4, l15 = lane & 15;
  const int win = blockIdx.x & 1023, h = blockIdx.x >> 10;
  const f32x4 fzero = {0.f, 0.f, 0.f, 0.f};

  // ---- A-fragments: coalesced loads from fragment-ordered xg ----
  bf16x8 aF[2][4];
#pragma unroll
  for (int s = 0; s < 2; ++s) {
    const unsigned short* xw = xg + ((size_t)(s * 1024 + win)) * 8192;
#pragma unroll
    for (int kk = 0; kk < 4; ++kk)
      aF[s][kk] = *(const bf16x8*)(xw + (wid * 4 + kk) * 512 + lane * 8);
  }

  // ---- QKV: M=16/wave per stream, N=128 (4 comps x 32), K=128 ----
  {
    f32x4 acc[2][8];
#pragma unroll
    for (int s = 0; s < 2; ++s)
#pragma unroll
      for (int n = 0; n < 8; ++n) acc[s][n] = fzero;
    __builtin_amdgcn_s_setprio(1);
#pragma unroll
    for (int kk = 0; kk < 4; ++kk)
#pragma unroll
      for (int nf = 0; nf < 8; ++nf) {
        const int frag = (((nf >> 1) * 4 + h) * 2 + (nf & 1)) * 4 + kk;
        bf16x8 bb = *(const bf16x8*)(Wqkvf + frag * 512 + lane * 8);
        acc[0][nf] = __builtin_amdgcn_mfma_f32_16x16x32_bf16(aF[0][kk], bb, acc[0][nf], 0, 0, 0);
        acc[1][nf] = __builtin_amdgcn_mfma_f32_16x16x32_bf16(aF[1][kk], bb, acc[1][nf], 0, 0, 0);
      }
    __builtin_amdgcn_s_setprio(0);
    float bv[8];
#pragma unroll
    for (int nf = 0; nf < 8; ++nf) bv[nf] = bqkv[(nf >> 1) * 128 + h * 32 + (nf & 1) * 16 + l15];
#pragma unroll
    for (int s = 0; s < 2; ++s)
#pragma unroll
      for (int r = 0; r < 4; ++r) {
        const int tw = wid * 16 + l4 * 4 + r;
        ldst32q(smem[s] + 0,    tw, 2 * l15, pk2(acc[s][0][r] + bv[0], acc[s][1][r] + bv[1]));
        ldst32q(smem[s] + 4096, tw, 2 * l15, pk2(acc[s][2][r] + bv[2], acc[s][3][r] + bv[3]));
        ldst32q(smem[s] + 2048, tw, 2 * l15, pk2(acc[s][6][r] + bv[6], acc[s][7][r] + bv[7]));
        const int vc = 16 * l4 + 4 * r + wid;  // vt token col in pi3 order
        ldss(smem[s] + 8192, l15,      64, vc, 7, f2bf(acc[s][4][r] + bv[4]));
        ldss(smem[s] + 8192, 16 + l15, 64, vc, 7, f2bf(acc[s][5][r] + bv[5]));
      }
  }
  __syncthreads();

  // ---- scores: wave -> (stream s, kind); barrier deferred to just before P-write ----
  const int s = wid >> 1, kind = wid & 1;
  bf16x8 aR[4], kR[4];
  {
    const unsigned short* Ab = kind ? (smem[1 - s] + 2048) : (smem[s] + 0);
    const unsigned short* Kb = smem[s] + 4096;
#pragma unroll
    for (int mf = 0; mf < 4; ++mf) aR[mf] = ldsvq(Ab, mf * 16 + l15, l4 * 8);
#pragma unroll
    for (int nf = 0; nf < 4; ++nf) kR[nf] = ldsvq(Kb, nf * 16 + l15, l4 * 8);
  }

  f32x4 sc[4][4];
#pragma unroll
  for (int mf = 0; mf < 4; ++mf)
#pragma unroll
    for (int nf = 0; nf < 4; ++nf) sc[mf][nf] = fzero;
  __builtin_amdgcn_s_setprio(1);
#pragma unroll
  for (int mf = 0; mf < 4; ++mf)
#pragma unroll
    for (int nf = 0; nf < 4; ++nf)
      sc[mf][nf] = __builtin_amdgcn_mfma_f32_16x16x32_bf16(aR[mf], kR[nf], sc[mf][nf], 0, 0, 0);
  __builtin_amdgcn_s_setprio(0);

  if (s == 0 && kind == 0) {  // rel-pos bias only on the r-branch (log2e-scaled)
#pragma unroll
    for (int mf = 0; mf < 4; ++mf)
#pragma unroll
      for (int nf = 0; nf < 4; ++nf)
#pragma unroll
        for (int r = 0; r < 4; ++r) {
          int row = mf * 16 + l4 * 4 + r, col = nf * 16 + l15;
          sc[mf][nf][r] += biasmat[(h * 64 + row) * 64 + col];
        }
  }
  // softmax (base-2 domain, no max subtraction: |S| << 1 so exp2 is exact fp32)
#pragma unroll
  for (int mf = 0; mf < 4; ++mf) {
#pragma unroll
    for (int r = 0; r < 4; ++r) {
      float e0 = __builtin_amdgcn_exp2f(sc[mf][0][r]);
      float e1 = __builtin_amdgcn_exp2f(sc[mf][1][r]);
      float e2 = __builtin_amdgcn_exp2f(sc[mf][2][r]);
      float e3 = __builtin_amdgcn_exp2f(sc[mf][3][r]);
      float sm = e0 + e1 + e2 + e3;
      sm += __shfl_xor(sm, 1); sm += __shfl_xor(sm, 2);
      sm += __shfl_xor(sm, 4); sm += __shfl_xor(sm, 8);
      float inv = __builtin_amdgcn_rcpf(sm);
      sc[mf][0][r] = e0 * inv; sc[mf][1][r] = e1 * inv;
      sc[mf][2][r] = e2 * inv; sc[mf][3][r] = e3 * inv;
    }
  }
  __syncthreads();  // all waves' q/q2/k reads done before P overwrites them
  // write Pa (kind0) / Pb (kind1), cols in pi3 order: col' = 4*l15 + nf, b64 packed
  {
    unsigned short* Ptgt = smem[s] + (kind ? 4096 : 0);
#pragma unroll
    for (int mf = 0; mf < 4; ++mf)
#pragma unroll
      for (int r = 0; r < 4; ++r)
        ldst64(Ptgt, mf * 16 + l4 * 4 + r, 64, 4 * l15, 7,
               pk2(sc[mf][0][r], sc[mf][1][r]), pk2(sc[mf][2][r], sc[mf][3][r]));
  }
  __syncthreads();

  // ---- PV: wave handles rows kind*32..+32; K=128 over Pa then Pb ----
  {
    const unsigned short* Vt = smem[s] + 8192;
    bf16x8 vR[2][2];
#pragma unroll
    for (int kk = 0; kk < 2; ++kk)
#pragma unroll
      for (int nf = 0; nf < 2; ++nf) vR[kk][nf] = ldsv(Vt, nf * 16 + l15, 64, kk * 32 + l4 * 8, 7);
    f32x4 pv[2][2];
    pv[0][0] = fzero; pv[0][1] = fzero; pv[1][0] = fzero; pv[1][1] = fzero;
    __builtin_amdgcn_s_setprio(1);
#pragma unroll
    for (int pb_i = 0; pb_i < 2; ++pb_i) {
      const unsigned short* Pbuf = smem[s] + pb_i * 4096;
#pragma unroll
      for (int kk = 0; kk < 2; ++kk) {
        bf16x8 pa0 = ldsv(Pbuf, kind * 32 + l15, 64, kk * 32 + l4 * 8, 7);
        bf16x8 pa1 = ldsv(Pbuf, kind * 32 + 16 + l15, 64, kk * 32 + l4 * 8, 7);
#pragma unroll
        for (int nf = 0; nf < 2; ++nf) {
          pv[0][nf] = __builtin_amdgcn_mfma_f32_16x16x32_bf16(pa0, vR[kk][nf], pv[0][nf], 0, 0, 0);
          pv[1][nf] = __builtin_amdgcn_mfma_f32_16x16x32_bf16(pa1, vR[kk][nf], pv[1][nf], 0, 0, 0);
        }
      }
    }
    __builtin_amdgcn_s_setprio(0);
    // aout channels in pi1 order within this head's 32-chunk: c' = h*32 + 2*l15 + nf
#pragma unroll
    for (int mf = 0; mf < 2; ++mf)
#pragma unroll
      for (int r = 0; r < 4; ++r) {
        int tw = kind * 32 + mf * 16 + l4 * 4 + r;
        *(unsigned int*)(aout + ((size_t)s * 65536 + (size_t)win * 64 + tw) * 128 + h * 32 + 2 * l15) =
            pk2(pv[mf][0][r], pv[mf][1][r]);
      }
  }
}

// ---------------- proj GEMM + bf16 residual + fused LN2 -> xn2; val -> bf16 xv ----------------
__global__ void __launch_bounds__(256, 4) proj_kernel(
    const unsigned short* __restrict__ aout, const unsigned short* __restrict__ Wprojf,
    const float* __restrict__ projb,
    const unsigned short* __restrict__ xb,
    const float* __restrict__ n2w, const float* __restrict__ n2b,
    unsigned short* __restrict__ xv, unsigned short* __restrict__ xn2)
{
  const int tid = threadIdx.x, wid = tid >> 6, lane = tid & 63;
  const int l4 = lane >> 4, l15 = lane & 15;
  const int s = blockIdx.x >> 9, blk = blockIdx.x & 511;
  const int row0 = blk * 128 + wid * 32;
  const unsigned short* A = aout + (size_t)s * 65536 * 128;
  const f32x4 fzero = {0.f, 0.f, 0.f, 0.f};

  bf16x8 aF[2][4];
#pragma unroll
  for (int mf = 0; mf < 2; ++mf)
#pragma unroll
    for (int kk = 0; kk < 4; ++kk)
      aF[mf][kk] = *(const bf16x8*)(A + (size_t)(row0 + mf * 16 + l15) * 128 + kk * 32 + l4 * 8);

  f32x4 acc[2][8];
#pragma unroll
  for (int mf = 0; mf < 2; ++mf)
#pragma unroll
    for (int nf = 0; nf < 8; ++nf) acc[mf][nf] = fzero;
#pragma unroll
  for (int kk = 0; kk < 4; ++kk)
#pragma unroll
    for (int nf = 0; nf < 8; ++nf) {
      bf16x8 bb = *(const bf16x8*)(Wprojf + (nf * 4 + kk) * 512 + lane * 8);
      acc[0][nf] = __builtin_amdgcn_mfma_f32_16x16x32_bf16(aF[0][kk], bb, acc[0][nf], 0, 0, 0);
      acc[1][nf] = __builtin_amdgcn_mfma_f32_16x16x32_bf16(aF[1][kk], bb, acc[1][nf], 0, 0, 0);
    }

  float pbv[8], w2v[8], b2v[8];
#pragma unroll
  for (int nf = 0; nf < 8; ++nf) {
    int col = nf * 16 + l15;
    pbv[nf] = projb[col]; w2v[nf] = n2w[col]; b2v[nf] = n2b[col];
  }
#pragma unroll
  for (int mf = 0; mf < 2; ++mf)
#pragma unroll
    for (int r = 0; r < 4; ++r) {
      int t = row0 + mf * 16 + l4 * 4 + r;
      int w2 = t >> 6, tk = t & 63;
      int b2 = w2 >> 8, hb = (w2 >> 4) & 15, wb = w2 & 15;
      int grow = b2 * 16384 + hb * 1024 + (tk >> 3) * 128 + wb * 8 + (tk & 7);
      float v[8];
      float sum = 0.f, ssq = 0.f;
#pragma unroll
      for (int nf = 0; nf < 8; ++nf) {
        size_t off = ((size_t)s * 65536 + grow) * 128 + nf * 16 + l15;
        float val = acc[mf][nf][r] + pbv[nf] + bf2f(xb[off]);
        v[nf] = val; sum += val; ssq += val * val;
      }
      // val -> bf16 at LINEAR row grow (mlp reads it at out-row order)
#pragma unroll
      for (int nf = 0; nf < 8; ++nf)
        xv[((size_t)s * 65536 + grow) * 128 + nf * 16 + l15] = f2bf(v[nf]);
      sum += __shfl_xor(sum, 1); sum += __shfl_xor(sum, 2);
      sum += __shfl_xor(sum, 4); sum += __shfl_xor(sum, 8);
      ssq += __shfl_xor(ssq, 1); ssq += __shfl_xor(ssq, 2);
      ssq += __shfl_xor(ssq, 4); ssq += __shfl_xor(ssq, 8);
      float mean = sum * (1.f / 128.f);
      float var = ssq * (1.f / 128.f) - mean * mean;
      float rs = rsqrtf(var + 1e-5f);
      float g[8];
#pragma unroll
      for (int nf = 0; nf < 8; ++nf) g[nf] = (v[nf] - mean) * rs * w2v[nf] + b2v[nf];
      size_t fidx = ((size_t)s * 4096 + (grow >> 4)) * 4 + (l15 >> 2);
      *(bf16x8*)(xn2 + fidx * 512 + ((l15 & 3) * 16 + (grow & 15)) * 8) = pack8(g);
    }
}

// ---------------- MLP v2: register-resident weights; 512 blocks x 256 tokens ----------------
__global__ void __launch_bounds__(512, 2) mlp_kernel(
    const unsigned short* __restrict__ xn2, const unsigned short* __restrict__ xv,
    const unsigned short* __restrict__ Wfc1f, const float* __restrict__ fc1b,
    const unsigned short* __restrict__ Wfc2f, const float* __restrict__ fc2b,
    float* __restrict__ out)
{
  __shared__ unsigned short hbuf[32 * 512];  // 32KB (mask 7), cols in 8-wave pack order
  const int tid = threadIdx.x, wid = tid >> 6, lane = tid & 63;
  const int l4 = lane >> 4, l15 = lane & 15;
  const f32x4 fzero = {0.f, 0.f, 0.f, 0.f};

  bf16x8 wf1[16], wf2[16];
#pragma unroll
  for (int q = 0; q < 16; ++q)
    wf1[q] = *(const bf16x8*)(Wfc1f + (size_t)((wid * 4 + (q >> 2)) * 4 + (q & 3)) * 512 + lane * 8);
#pragma unroll
  for (int kk = 0; kk < 16; ++kk)
    wf2[kk] = *(const bf16x8*)(Wfc2f + (size_t)(wid * 16 + kk) * 512 + lane * 8);

  float b1v[4];
#pragma unroll
  for (int nf = 0; nf < 4; ++nf) b1v[nf] = fc1b[wid * 64 + nf * 16 + l15];
  const float b2c = fc2b[wid * 16 + l15];
  const int ocol = wid * 16 + l15;

  const size_t tokbase = (size_t)blockIdx.x * 256;

  for (int it = 0; it < 8; ++it) {
    if (it) __syncthreads();  // hbuf reuse guard
    const size_t tb = tokbase + it * 32;
    // ---- fc1 + gelu ----
    f32x4 acc[2][4];
#pragma unroll
    for (int mf = 0; mf < 2; ++mf)
#pragma unroll
      for (int nf = 0; nf < 4; ++nf) acc[mf][nf] = fzero;
#pragma unroll
    for (int mf = 0; mf < 2; ++mf)
#pragma unroll
      for (int kk = 0; kk < 4; ++kk) {
        bf16x8 a = *(const bf16x8*)(xn2 + (((tb >> 4) + mf) * 4 + kk) * 512 + lane * 8);
#pragma unroll
        for (int nf = 0; nf < 4; ++nf)
          acc[mf][nf] = __builtin_amdgcn_mfma_f32_16x16x32_bf16(a, wf1[nf * 4 + kk], acc[mf][nf], 0, 0, 0);
      }
#pragma unroll
    for (int mf = 0; mf < 2; ++mf)
#pragma unroll
      for (int r = 0; r < 4; ++r) {
        float g[4];
#pragma unroll
        for (int nf = 0; nf < 4; ++nf) {
          float vv = acc[mf][nf][r] + b1v[nf];
          float x2 = vv * vv;
          float u2 = vv * fmaf(-0.10294455f, x2, -2.3022078f);
          float e = __builtin_amdgcn_exp2f(u2);
          g[nf] = vv * __builtin_amdgcn_rcpf(1.f + e);
        }
        ldst64(hbuf, mf * 16 + l4 * 4 + r, 512, wid * 64 + l15 * 4, 7,
               pk2(g[0], g[1]), pk2(g[2], g[3]));
      }
    __syncthreads();
    // ---- fc2 + bf16 residual (pure store to out) ----
    f32x4 a2[2];
    a2[0] = fzero; a2[1] = fzero;
#pragma unroll
    for (int kk = 0; kk < 16; ++kk) {
      bf16x8 h0 = ldsv(hbuf, l15, 512, kk * 32 + l4 * 8, 7);
      bf16x8 h1 = ldsv(hbuf, 16 + l15, 512, kk * 32 + l4 * 8, 7);
      a2[0] = __builtin_amdgcn_mfma_f32_16x16x32_bf16(h0, wf2[kk], a2[0], 0, 0, 0);
      a2[1] = __builtin_amdgcn_mfma_f32_16x16x32_bf16(h1, wf2[kk], a2[1], 0, 0, 0);
    }
#pragma unroll
    for (int mf = 0; mf < 2; ++mf)
#pragma unroll
      for (int r = 0; r < 4; ++r) {
        int row = mf * 16 + l4 * 4 + r;
        size_t off = (tb + row) * 128 + ocol;
        float res = bf2f(xv[off]);
        out[off] = a2[mf][r] + b2c + res;
      }
  }
}

extern "C" void kernel_launch(void* const* d_in, const int* in_sizes, int n_in,
                              void* d_out, int out_size, void* d_ws, size_t ws_size,
                              hipStream_t stream) {
  const float* x    = (const float*)d_in[0];
  const float* dd   = (const float*)d_in[1];
  const float* rpb  = (const float*)d_in[2];
  const float* n1w  = (const float*)d_in[3];
  const float* n1b  = (const float*)d_in[4];
  const float* n2w  = (const float*)d_in[5];
  const float* n2b  = (const float*)d_in[6];
  const float* qkvw = (const float*)d_in[7];
  const float* qkvb = (const float*)d_in[8];
  const float* pw   = (const float*)d_in[9];
  const float* pb   = (const float*)d_in[10];
  const float* f1w  = (const float*)d_in[11];
  const float* f1b  = (const float*)d_in[12];
  const float* f2w  = (const float*)d_in[13];
  const float* f2b  = (const float*)d_in[14];
  float* out = (float*)d_out;
  char* ws = (char*)d_ws;
  unsigned short* Wqkvf  = (unsigned short*)(ws);
  unsigned short* Wprojf = (unsigned short*)(ws + 131072);
  unsigned short* Wfc1f  = (unsigned short*)(ws + 163840);
  unsigned short* Wfc2f  = (unsigned short*)(ws + 294912);
  float* bqkv            = (float*)(ws + 425984);
  float* biasmat         = (float*)(ws + 428032);
  unsigned short* aout   = (unsigned short*)(ws + 524288);              // 33.5MB
  unsigned short* xn2    = (unsigned short*)(ws + 524288 + 33554432);   // 33.5MB
  unsigned short* xv     = (unsigned short*)(ws + 524288 + 67108864);   // 33.5MB
  // d_out (67MB) split: xg (lower 33.5MB) + xb (upper 33.5MB); both dead before mlp writes out
  unsigned short* xg     = (unsigned short*)d_out;
  unsigned short* xb     = (unsigned short*)d_out + 16777216;

  prep_kernel<<<dim3(899), dim3(256), 0, stream>>>(qkvw, qkvb, pw, f1w, f2w, rpb,
                                                   Wqkvf, Wprojf, Wfc1f, Wfc2f, bqkv, biasmat);
  ln1_kernel<<<dim3(2048), dim3(256), 0, stream>>>(x, dd, n1w, n1b, xg, xb);
  attn_kernel<<<dim3(4096), dim3(256), 0, stream>>>(xg, Wqkvf, bqkv, biasmat, aout);
  proj_kernel<<<dim3(1024), dim3(256), 0, stream>>>(aout, Wprojf, pb, xb, n2w, n2b, xv, xn2);
  mlp_kernel<<<dim3(512), dim3(512), 0, stream>>>(xn2, xv, Wfc1f, f1b, Wfc2f, f2b, out);
}

// Round 17
// 201.043 us; speedup vs baseline: 1.0100x; 1.0100x over previous
//
#include <hip/hip_runtime.h>
#include <hip/hip_bf16.h>
#include <math.h>

typedef short bf16x8 __attribute__((ext_vector_type(8)));
typedef float f32x4 __attribute__((ext_vector_type(4)));

#define QKSCALE_L2E 0.25505402227437564f  // 32^-0.5 * log2(e)
#define LOG2E 1.4426950408889634f

__device__ __forceinline__ unsigned short f2bf(float f) {
  __hip_bfloat16 h = __float2bfloat16(f);
  return *reinterpret_cast<unsigned short*>(&h);
}
__device__ __forceinline__ float bf2f(unsigned short h) {
  return __uint_as_float(((unsigned int)h) << 16);
}
__device__ __forceinline__ unsigned int pk2(float lo, float hi) {
  __hip_bfloat162 h = __float22bfloat162_rn(make_float2(lo, hi));
  return *reinterpret_cast<unsigned int*>(&h);
}
__device__ __forceinline__ bf16x8 pack8(const float* g) {
  union { unsigned int u[4]; bf16x8 v; } t;
  t.u[0] = pk2(g[0], g[1]); t.u[1] = pk2(g[2], g[3]);
  t.u[2] = pk2(g[4], g[5]); t.u[3] = pk2(g[6], g[7]);
  return t.v;
}

// XOR-swizzled LDS helpers (bf16 tiles, swizzle in 16B units on row bits)
__device__ __forceinline__ bf16x8 ldsv(const unsigned short* base, int row, int strideHalfs, int kHalf, int swzMask) {
  int byte = row * strideHalfs * 2 + kHalf * 2;
  byte ^= (row & swzMask) << 4;
  return *(const bf16x8*)((const char*)base + byte);
}
__device__ __forceinline__ void ldss(unsigned short* base, int row, int strideHalfs, int col, int swzMask, unsigned short v) {
  int byte = row * strideHalfs * 2 + col * 2;
  byte ^= (row & swzMask) << 4;
  *(unsigned short*)((char*)base + byte) = v;
}
__device__ __forceinline__ void ldst64(unsigned short* base, int row, int strideHalfs, int colHalf, int swzMask, unsigned int lo, unsigned int hi) {
  int byte = row * strideHalfs * 2 + colHalf * 2;
  byte ^= (row & swzMask) << 4;
  uint2 val; val.x = lo; val.y = hi;
  *(uint2*)((char*)base + byte) = val;
}
// q/k/q2 [64][32-half] tiles: bank-bit-4 swizzle -> 2-way (free) b32 stores,
// optimal-b128 reads. byte ^= ((row>>2)&1)<<6 is a bijection on the 4KB tile.
__device__ __forceinline__ void ldst32q(unsigned short* base, int row, int colHalf, unsigned int v) {
  int byte = row * 64 + colHalf * 2;
  byte ^= ((row >> 2) & 1) << 6;
  *(unsigned int*)((char*)base + byte) = v;
}
__device__ __forceinline__ bf16x8 ldsvq(const unsigned short* base, int row, int kHalf) {
  int byte = row * 64 + kHalf * 2;
  byte ^= ((row >> 2) & 1) << 6;
  return *(const bf16x8*)((const char*)base + byte);
}

// ---------------- prep: fragment-ordered bf16 weights ----------------
__global__ void prep_kernel(
    const float* __restrict__ qkv1_w, const float* __restrict__ qkv1_b,
    const float* __restrict__ proj_w, const float* __restrict__ fc1_w,
    const float* __restrict__ fc2_w,  const float* __restrict__ rpb,
    unsigned short* __restrict__ Wqkvf, unsigned short* __restrict__ Wprojf,
    unsigned short* __restrict__ Wfc1f, unsigned short* __restrict__ Wfc2f,
    float* __restrict__ bqkv, float* __restrict__ biasmat)
{
  int i = blockIdx.x * 256 + threadIdx.x;
  if (i < 65536) {  // Wqkvf: frag = ((comp*4+h)*2+sub16)*4+kk
    int j = i & 7, lane = (i >> 3) & 63, kk = (i >> 9) & 3;
    int sub16 = (i >> 11) & 1, h = (i >> 12) & 3, comp = i >> 14;
    int row = comp * 128 + h * 32 + sub16 * 16 + (lane & 15);
    int col = kk * 32 + (lane >> 4) * 8 + j;
    float sc = (comp == 0 || comp == 3) ? QKSCALE_L2E : 1.f;
    Wqkvf[i] = f2bf(qkv1_w[row * 128 + col] * sc);
  }
  int o = i - 65536;
  if (o >= 0 && o < 16384) {  // Wprojf: frag = nf*4+kk ; k-col pi1-permuted
    int j = o & 7, lane = (o >> 3) & 63, kk = (o >> 9) & 3, nf = o >> 11;
    int row = nf * 16 + (lane & 15);
    int cp = kk * 32 + (lane >> 4) * 8 + j;
    int H = cp >> 5, q = cp & 31, a = q >> 1, b = q & 1;
    Wprojf[o] = f2bf(proj_w[row * 128 + H * 32 + 16 * b + a]);
  }
  o -= 16384;
  if (o >= 0 && o < 65536) {  // Wfc1f: frag = n16*4+kk ; k-col pi-permuted
    int j = o & 7, lane = (o >> 3) & 63, kk = (o >> 9) & 3, n16 = o >> 11;
    int row = n16 * 16 + (lane & 15);
    int cp = kk * 32 + (lane >> 4) * 8 + j;
    Wfc1f[o] = f2bf(fc1_w[row * 128 + 16 * (cp & 7) + (cp >> 3)]);
  }
  o -= 65536;
  if (o >= 0 && o < 65536) {  // Wfc2f: frag = n8*16+kk ; k-col matches 8-wave hbuf pack
    int j = o & 7, lane = (o >> 3) & 63, kk = (o >> 9) & 15, n8 = o >> 13;
    int row = n8 * 16 + (lane & 15);
    int m = kk * 32 + (lane >> 4) * 8 + j;
    int src = (m >> 6) * 64 + 16 * (m & 3) + ((m >> 2) & 15);
    Wfc2f[o] = f2bf(fc2_w[row * 512 + src]);
  }
  o -= 65536;
  if (o >= 0 && o < 512) {
    int comp = o >> 7;
    bqkv[o] = qkv1_b[o] * ((comp == 0 || comp == 3) ? QKSCALE_L2E : 1.f);
  }
  o -= 512;
  if (o >= 0 && o < 16384) {  // biasmat[h][n][m], scaled by log2(e)
    int hh = o >> 12, n = (o >> 6) & 63, m = o & 63;
    int di = (n >> 3) - (m >> 3) + 7, dj = (n & 7) - (m & 7) + 7;
    biasmat[o] = rpb[(di * 15 + dj) * 4 + hh] * LOG2E;
  }
}

// ---------------- LN1 -> fragment-ordered bf16 tokens (xg) + raw-x bf16 copy (xb) ----------------
__global__ void __launch_bounds__(256) ln1_kernel(
    const float* __restrict__ x_in, const float* __restrict__ d_in_,
    const float* __restrict__ n1w, const float* __restrict__ n1b,
    unsigned short* __restrict__ xg, unsigned short* __restrict__ xb)
{
  const int s = blockIdx.x >> 10;
  const int row0 = (blockIdx.x & 1023) * 64;
  const int t = threadIdx.x >> 2, q4 = threadIdx.x & 3;
  const int grow = row0 + t;
  const int b2 = grow >> 14, rem = grow & 16383;
  const int gy = rem >> 7, gx = rem & 127;
  const int win = b2 * 256 + (gy >> 3) * 16 + (gx >> 3);
  const int tok = (gy & 7) * 8 + (gx & 7);
  const float* src = (s ? d_in_ : x_in) + (size_t)grow * 128 + q4 * 32;
  float v[32];
  float sum = 0.f, ss = 0.f;
#pragma unroll
  for (int i = 0; i < 8; ++i) {
    float4 f = ((const float4*)src)[i];
    v[i * 4 + 0] = f.x; v[i * 4 + 1] = f.y; v[i * 4 + 2] = f.z; v[i * 4 + 3] = f.w;
    sum += f.x + f.y + f.z + f.w;
    ss += f.x * f.x + f.y * f.y + f.z * f.z + f.w * f.w;
  }
  sum += __shfl_xor(sum, 1); sum += __shfl_xor(sum, 2);
  ss  += __shfl_xor(ss, 1);  ss  += __shfl_xor(ss, 2);
  float mean = sum * (1.f / 128.f);
  float var = ss * (1.f / 128.f) - mean * mean;
  float rs = rsqrtf(var + 1e-5f);
  // raw-x bf16 copy, linear row order (proj's residual base)
  unsigned short* xbd = xb + ((size_t)s * 65536 + grow) * 128 + q4 * 32;
#pragma unroll
  for (int i = 0; i < 4; ++i) *(bf16x8*)(xbd + i * 8) = pack8(v + i * 8);
  unsigned short* base = xg + ((size_t)(s * 1024 + win)) * 8192
                         + ((tok >> 4) * 4 + q4) * 512 + (tok & 15) * 8;
#pragma unroll
  for (int i = 0; i < 4; ++i) {
    float g[8];
#pragma unroll
    for (int jj = 0; jj < 8; ++jj) {
      int c = q4 * 32 + i * 8 + jj;
      g[jj] = (v[i * 8 + jj] - mean) * rs * n1w[c] + n1b[c];
    }
    *(bf16x8*)(base + i * 128) = pack8(g);
  }
}

// ---------------- attention: 1 block = (window, head), both streams (R12/R14 proven form) ----------------
// Head-major grid; deferred alias barrier; 2-way-store swizzle on q/k/q2. 40KB LDS.
__global__ void __launch_bounds__(256, 4) attn_kernel(
    const unsigned short* __restrict__ xg,
    const unsigned short* __restrict__ Wqkvf, const float* __restrict__ bqkv,
    const float* __restrict__ biasmat,
    unsigned short* __restrict__ aout)
{
  __shared__ unsigned short smem[2][10240];

  const int tid = threadIdx.x, wid = tid >> 6, lane = tid & 63;
  const int l4 = lane >> 4, l15 = lane & 15;
  const int win = blockIdx.x & 1023, h = blockIdx.x >> 10;
  const f32x4 fzero = {0.f, 0.f, 0.f, 0.f};

  // ---- A-fragments: coalesced loads from fragment-ordered xg ----
  bf16x8 aF[2][4];
#pragma unroll
  for (int s = 0; s < 2; ++s) {
    const unsigned short* xw = xg + ((size_t)(s * 1024 + win)) * 8192;
#pragma unroll
    for (int kk = 0; kk < 4; ++kk)
      aF[s][kk] = *(const bf16x8*)(xw + (wid * 4 + kk) * 512 + lane * 8);
  }

  // ---- QKV: M=16/wave per stream, N=128 (4 comps x 32), K=128 ----
  {
    f32x4 acc[2][8];
#pragma unroll
    for (int s = 0; s < 2; ++s)
#pragma unroll
      for (int n = 0; n < 8; ++n) acc[s][n] = fzero;
#pragma unroll
    for (int kk = 0; kk < 4; ++kk)
#pragma unroll
      for (int nf = 0; nf < 8; ++nf) {
        const int frag = (((nf >> 1) * 4 + h) * 2 + (nf & 1)) * 4 + kk;
        bf16x8 bb = *(const bf16x8*)(Wqkvf + frag * 512 + lane * 8);
        acc[0][nf] = __builtin_amdgcn_mfma_f32_16x16x32_bf16(aF[0][kk], bb, acc[0][nf], 0, 0, 0);
        acc[1][nf] = __builtin_amdgcn_mfma_f32_16x16x32_bf16(aF[1][kk], bb, acc[1][nf], 0, 0, 0);
      }
    float bv[8];
#pragma unroll
    for (int nf = 0; nf < 8; ++nf) bv[nf] = bqkv[(nf >> 1) * 128 + h * 32 + (nf & 1) * 16 + l15];
#pragma unroll
    for (int s = 0; s < 2; ++s)
#pragma unroll
      for (int r = 0; r < 4; ++r) {
        const int tw = wid * 16 + l4 * 4 + r;
        ldst32q(smem[s] + 0,    tw, 2 * l15, pk2(acc[s][0][r] + bv[0], acc[s][1][r] + bv[1]));
        ldst32q(smem[s] + 4096, tw, 2 * l15, pk2(acc[s][2][r] + bv[2], acc[s][3][r] + bv[3]));
        ldst32q(smem[s] + 2048, tw, 2 * l15, pk2(acc[s][6][r] + bv[6], acc[s][7][r] + bv[7]));
        const int vc = 16 * l4 + 4 * r + wid;  // vt token col in pi3 order
        ldss(smem[s] + 8192, l15,      64, vc, 7, f2bf(acc[s][4][r] + bv[4]));
        ldss(smem[s] + 8192, 16 + l15, 64, vc, 7, f2bf(acc[s][5][r] + bv[5]));
      }
  }
  __syncthreads();

  // ---- scores: wave -> (stream s, kind); barrier deferred to just before P-write ----
  const int s = wid >> 1, kind = wid & 1;
  bf16x8 aR[4], kR[4];
  {
    const unsigned short* Ab = kind ? (smem[1 - s] + 2048) : (smem[s] + 0);
    const unsigned short* Kb = smem[s] + 4096;
#pragma unroll
    for (int mf = 0; mf < 4; ++mf) aR[mf] = ldsvq(Ab, mf * 16 + l15, l4 * 8);
#pragma unroll
    for (int nf = 0; nf < 4; ++nf) kR[nf] = ldsvq(Kb, nf * 16 + l15, l4 * 8);
  }

  f32x4 sc[4][4];
#pragma unroll
  for (int mf = 0; mf < 4; ++mf)
#pragma unroll
    for (int nf = 0; nf < 4; ++nf) sc[mf][nf] = fzero;
#pragma unroll
  for (int mf = 0; mf < 4; ++mf)
#pragma unroll
    for (int nf = 0; nf < 4; ++nf)
      sc[mf][nf] = __builtin_amdgcn_mfma_f32_16x16x32_bf16(aR[mf], kR[nf], sc[mf][nf], 0, 0, 0);

  if (s == 0 && kind == 0) {  // rel-pos bias only on the r-branch (log2e-scaled)
#pragma unroll
    for (int mf = 0; mf < 4; ++mf)
#pragma unroll
      for (int nf = 0; nf < 4; ++nf)
#pragma unroll
        for (int r = 0; r < 4; ++r) {
          int row = mf * 16 + l4 * 4 + r, col = nf * 16 + l15;
          sc[mf][nf][r] += biasmat[(h * 64 + row) * 64 + col];
        }
  }
  // softmax (base-2 domain): shared upper-bound max per (mf, l4-quad), exact row sums
#pragma unroll
  for (int mf = 0; mf < 4; ++mf) {
    float M = sc[mf][0][0];
#pragma unroll
    for (int nf = 0; nf < 4; ++nf)
#pragma unroll
      for (int r = 0; r < 4; ++r) M = fmaxf(M, sc[mf][nf][r]);
    M = fmaxf(M, __shfl_xor(M, 1));
    M = fmaxf(M, __shfl_xor(M, 2));
    M = fmaxf(M, __shfl_xor(M, 4));
    M = fmaxf(M, __shfl_xor(M, 8));
#pragma unroll
    for (int r = 0; r < 4; ++r) {
      float e0 = __builtin_amdgcn_exp2f(sc[mf][0][r] - M);
      float e1 = __builtin_amdgcn_exp2f(sc[mf][1][r] - M);
      float e2 = __builtin_amdgcn_exp2f(sc[mf][2][r] - M);
      float e3 = __builtin_amdgcn_exp2f(sc[mf][3][r] - M);
      float sm = e0 + e1 + e2 + e3;
      sm += __shfl_xor(sm, 1); sm += __shfl_xor(sm, 2);
      sm += __shfl_xor(sm, 4); sm += __shfl_xor(sm, 8);
      float inv = __builtin_amdgcn_rcpf(sm);
      sc[mf][0][r] = e0 * inv; sc[mf][1][r] = e1 * inv;
      sc[mf][2][r] = e2 * inv; sc[mf][3][r] = e3 * inv;
    }
  }
  __syncthreads();  // all waves' q/q2/k reads done before P overwrites them
  // write Pa (kind0) / Pb (kind1), cols in pi3 order: col' = 4*l15 + nf, b64 packed
  {
    unsigned short* Ptgt = smem[s] + (kind ? 4096 : 0);
#pragma unroll
    for (int mf = 0; mf < 4; ++mf)
#pragma unroll
      for (int r = 0; r < 4; ++r)
        ldst64(Ptgt, mf * 16 + l4 * 4 + r, 64, 4 * l15, 7,
               pk2(sc[mf][0][r], sc[mf][1][r]), pk2(sc[mf][2][r], sc[mf][3][r]));
  }
  __syncthreads();

  // ---- PV: wave handles rows kind*32..+32; K=128 over Pa then Pb ----
  {
    const unsigned short* Vt = smem[s] + 8192;
    bf16x8 vR[2][2];
#pragma unroll
    for (int kk = 0; kk < 2; ++kk)
#pragma unroll
      for (int nf = 0; nf < 2; ++nf) vR[kk][nf] = ldsv(Vt, nf * 16 + l15, 64, kk * 32 + l4 * 8, 7);
    f32x4 pv[2][2];
    pv[0][0] = fzero; pv[0][1] = fzero; pv[1][0] = fzero; pv[1][1] = fzero;
#pragma unroll
    for (int pb_i = 0; pb_i < 2; ++pb_i) {
      const unsigned short* Pbuf = smem[s] + pb_i * 4096;
#pragma unroll
      for (int kk = 0; kk < 2; ++kk) {
        bf16x8 pa0 = ldsv(Pbuf, kind * 32 + l15, 64, kk * 32 + l4 * 8, 7);
        bf16x8 pa1 = ldsv(Pbuf, kind * 32 + 16 + l15, 64, kk * 32 + l4 * 8, 7);
#pragma unroll
        for (int nf = 0; nf < 2; ++nf) {
          pv[0][nf] = __builtin_amdgcn_mfma_f32_16x16x32_bf16(pa0, vR[kk][nf], pv[0][nf], 0, 0, 0);
          pv[1][nf] = __builtin_amdgcn_mfma_f32_16x16x32_bf16(pa1, vR[kk][nf], pv[1][nf], 0, 0, 0);
        }
      }
    }
    // aout channels in pi1 order within this head's 32-chunk: c' = h*32 + 2*l15 + nf
#pragma unroll
    for (int mf = 0; mf < 2; ++mf)
#pragma unroll
      for (int r = 0; r < 4; ++r) {
        int tw = kind * 32 + mf * 16 + l4 * 4 + r;
        *(unsigned int*)(aout + ((size_t)s * 65536 + (size_t)win * 64 + tw) * 128 + h * 32 + 2 * l15) =
            pk2(pv[mf][0][r], pv[mf][1][r]);
      }
  }
}

// ---------------- proj GEMM + bf16 residual + fused LN2 -> xn2; val -> bf16 xv ----------------
__global__ void __launch_bounds__(256, 4) proj_kernel(
    const unsigned short* __restrict__ aout, const unsigned short* __restrict__ Wprojf,
    const float* __restrict__ projb,
    const unsigned short* __restrict__ xb,
    const float* __restrict__ n2w, const float* __restrict__ n2b,
    unsigned short* __restrict__ xv, unsigned short* __restrict__ xn2)
{
  const int tid = threadIdx.x, wid = tid >> 6, lane = tid & 63;
  const int l4 = lane >> 4, l15 = lane & 15;
  const int s = blockIdx.x >> 9, blk = blockIdx.x & 511;
  const int row0 = blk * 128 + wid * 32;
  const unsigned short* A = aout + (size_t)s * 65536 * 128;
  const f32x4 fzero = {0.f, 0.f, 0.f, 0.f};

  bf16x8 aF[2][4];
#pragma unroll
  for (int mf = 0; mf < 2; ++mf)
#pragma unroll
    for (int kk = 0; kk < 4; ++kk)
      aF[mf][kk] = *(const bf16x8*)(A + (size_t)(row0 + mf * 16 + l15) * 128 + kk * 32 + l4 * 8);

  f32x4 acc[2][8];
#pragma unroll
  for (int mf = 0; mf < 2; ++mf)
#pragma unroll
    for (int nf = 0; nf < 8; ++nf) acc[mf][nf] = fzero;
#pragma unroll
  for (int kk = 0; kk < 4; ++kk)
#pragma unroll
    for (int nf = 0; nf < 8; ++nf) {
      bf16x8 bb = *(const bf16x8*)(Wprojf + (nf * 4 + kk) * 512 + lane * 8);
      acc[0][nf] = __builtin_amdgcn_mfma_f32_16x16x32_bf16(aF[0][kk], bb, acc[0][nf], 0, 0, 0);
      acc[1][nf] = __builtin_amdgcn_mfma_f32_16x16x32_bf16(aF[1][kk], bb, acc[1][nf], 0, 0, 0);
    }

  float pbv[8], w2v[8], b2v[8];
#pragma unroll
  for (int nf = 0; nf < 8; ++nf) {
    int col = nf * 16 + l15;
    pbv[nf] = projb[col]; w2v[nf] = n2w[col]; b2v[nf] = n2b[col];
  }
#pragma unroll
  for (int mf = 0; mf < 2; ++mf)
#pragma unroll
    for (int r = 0; r < 4; ++r) {
      int t = row0 + mf * 16 + l4 * 4 + r;
      int w2 = t >> 6, tk = t & 63;
      int b2 = w2 >> 8, hb = (w2 >> 4) & 15, wb = w2 & 15;
      int grow = b2 * 16384 + hb * 1024 + (tk >> 3) * 128 + wb * 8 + (tk & 7);
      float v[8];
      float sum = 0.f, ssq = 0.f;
#pragma unroll
      for (int nf = 0; nf < 8; ++nf) {
        size_t off = ((size_t)s * 65536 + grow) * 128 + nf * 16 + l15;
        float val = acc[mf][nf][r] + pbv[nf] + bf2f(xb[off]);
        v[nf] = val; sum += val; ssq += val * val;
      }
      // val -> bf16 at LINEAR row grow (mlp reads it at out-row order)
#pragma unroll
      for (int nf = 0; nf < 8; ++nf)
        xv[((size_t)s * 65536 + grow) * 128 + nf * 16 + l15] = f2bf(v[nf]);
      sum += __shfl_xor(sum, 1); sum += __shfl_xor(sum, 2);
      sum += __shfl_xor(sum, 4); sum += __shfl_xor(sum, 8);
      ssq += __shfl_xor(ssq, 1); ssq += __shfl_xor(ssq, 2);
      ssq += __shfl_xor(ssq, 4); ssq += __shfl_xor(ssq, 8);
      float mean = sum * (1.f / 128.f);
      float var = ssq * (1.f / 128.f) - mean * mean;
      float rs = rsqrtf(var + 1e-5f);
      float g[8];
#pragma unroll
      for (int nf = 0; nf < 8; ++nf) g[nf] = (v[nf] - mean) * rs * w2v[nf] + b2v[nf];
      size_t fidx = ((size_t)s * 4096 + (grow >> 4)) * 4 + (l15 >> 2);
      *(bf16x8*)(xn2 + fidx * 512 + ((l15 & 3) * 16 + (grow & 15)) * 8) = pack8(g);
    }
}

// ---------------- MLP v2: register-resident weights; 512 blocks x 256 tokens ----------------
__global__ void __launch_bounds__(512, 2) mlp_kernel(
    const unsigned short* __restrict__ xn2, const unsigned short* __restrict__ xv,
    const unsigned short* __restrict__ Wfc1f, const float* __restrict__ fc1b,
    const unsigned short* __restrict__ Wfc2f, const float* __restrict__ fc2b,
    float* __restrict__ out)
{
  __shared__ unsigned short hbuf[32 * 512];  // 32KB (mask 7), cols in 8-wave pack order
  const int tid = threadIdx.x, wid = tid >> 6, lane = tid & 63;
  const int l4 = lane >> 4, l15 = lane & 15;
  const f32x4 fzero = {0.f, 0.f, 0.f, 0.f};

  bf16x8 wf1[16], wf2[16];
#pragma unroll
  for (int q = 0; q < 16; ++q)
    wf1[q] = *(const bf16x8*)(Wfc1f + (size_t)((wid * 4 + (q >> 2)) * 4 + (q & 3)) * 512 + lane * 8);
#pragma unroll
  for (int kk = 0; kk < 16; ++kk)
    wf2[kk] = *(const bf16x8*)(Wfc2f + (size_t)(wid * 16 + kk) * 512 + lane * 8);

  float b1v[4];
#pragma unroll
  for (int nf = 0; nf < 4; ++nf) b1v[nf] = fc1b[wid * 64 + nf * 16 + l15];
  const float b2c = fc2b[wid * 16 + l15];
  const int ocol = wid * 16 + l15;

  const size_t tokbase = (size_t)blockIdx.x * 256;

  for (int it = 0; it < 8; ++it) {
    if (it) __syncthreads();  // hbuf reuse guard
    const size_t tb = tokbase + it * 32;
    // ---- fc1 + gelu ----
    f32x4 acc[2][4];
#pragma unroll
    for (int mf = 0; mf < 2; ++mf)
#pragma unroll
      for (int nf = 0; nf < 4; ++nf) acc[mf][nf] = fzero;
#pragma unroll
    for (int mf = 0; mf < 2; ++mf)
#pragma unroll
      for (int kk = 0; kk < 4; ++kk) {
        bf16x8 a = *(const bf16x8*)(xn2 + (((tb >> 4) + mf) * 4 + kk) * 512 + lane * 8);
#pragma unroll
        for (int nf = 0; nf < 4; ++nf)
          acc[mf][nf] = __builtin_amdgcn_mfma_f32_16x16x32_bf16(a, wf1[nf * 4 + kk], acc[mf][nf], 0, 0, 0);
      }
#pragma unroll
    for (int mf = 0; mf < 2; ++mf)
#pragma unroll
      for (int r = 0; r < 4; ++r) {
        float g[4];
#pragma unroll
        for (int nf = 0; nf < 4; ++nf) {
          float vv = acc[mf][nf][r] + b1v[nf];
          float x2 = vv * vv;
          float u2 = vv * fmaf(-0.10294455f, x2, -2.3022078f);
          float e = __builtin_amdgcn_exp2f(u2);
          g[nf] = vv * __builtin_amdgcn_rcpf(1.f + e);
        }
        ldst64(hbuf, mf * 16 + l4 * 4 + r, 512, wid * 64 + l15 * 4, 7,
               pk2(g[0], g[1]), pk2(g[2], g[3]));
      }
    __syncthreads();
    // ---- fc2 + bf16 residual (pure store to out) ----
    f32x4 a2[2];
    a2[0] = fzero; a2[1] = fzero;
#pragma unroll
    for (int kk = 0; kk < 16; ++kk) {
      bf16x8 h0 = ldsv(hbuf, l15, 512, kk * 32 + l4 * 8, 7);
      bf16x8 h1 = ldsv(hbuf, 16 + l15, 512, kk * 32 + l4 * 8, 7);
      a2[0] = __builtin_amdgcn_mfma_f32_16x16x32_bf16(h0, wf2[kk], a2[0], 0, 0, 0);
      a2[1] = __builtin_amdgcn_mfma_f32_16x16x32_bf16(h1, wf2[kk], a2[1], 0, 0, 0);
    }
#pragma unroll
    for (int mf = 0; mf < 2; ++mf)
#pragma unroll
      for (int r = 0; r < 4; ++r) {
        int row = mf * 16 + l4 * 4 + r;
        size_t off = (tb + row) * 128 + ocol;
        float res = bf2f(xv[off]);
        out[off] = a2[mf][r] + b2c + res;
      }
  }
}

extern "C" void kernel_launch(void* const* d_in, const int* in_sizes, int n_in,
                              void* d_out, int out_size, void* d_ws, size_t ws_size,
                              hipStream_t stream) {
  const float* x    = (const float*)d_in[0];
  const float* dd   = (const float*)d_in[1];
  const float* rpb  = (const float*)d_in[2];
  const float* n1w  = (const float*)d_in[3];
  const float* n1b  = (const float*)d_in[4];
  const float* n2w  = (const float*)d_in[5];
  const float* n2b  = (const float*)d_in[6];
  const float* qkvw = (const float*)d_in[7];
  const float* qkvb = (const float*)d_in[8];
  const float* pw   = (const float*)d_in[9];
  const float* pb   = (const float*)d_in[10];
  const float* f1w  = (const float*)d_in[11];
  const float* f1b  = (const float*)d_in[12];
  const float* f2w  = (const float*)d_in[13];
  const float* f2b  = (const float*)d_in[14];
  float* out = (float*)d_out;
  char* ws = (char*)d_ws;
  unsigned short* Wqkvf  = (unsigned short*)(ws);
  unsigned short* Wprojf = (unsigned short*)(ws + 131072);
  unsigned short* Wfc1f  = (unsigned short*)(ws + 163840);
  unsigned short* Wfc2f  = (unsigned short*)(ws + 294912);
  float* bqkv            = (float*)(ws + 425984);
  float* biasmat         = (float*)(ws + 428032);
  unsigned short* aout   = (unsigned short*)(ws + 524288);              // 33.5MB
  unsigned short* xn2    = (unsigned short*)(ws + 524288 + 33554432);   // 33.5MB
  unsigned short* xv     = (unsigned short*)(ws + 524288 + 67108864);   // 33.5MB
  // d_out (67MB) split: xg (lower 33.5MB) + xb (upper 33.5MB); both dead before mlp writes out
  unsigned short* xg     = (unsigned short*)d_out;
  unsigned short* xb     = (unsigned short*)d_out + 16777216;

  prep_kernel<<<dim3(899), dim3(256), 0, stream>>>(qkvw, qkvb, pw, f1w, f2w, rpb,
                                                   Wqkvf, Wprojf, Wfc1f, Wfc2f, bqkv, biasmat);
  ln1_kernel<<<dim3(2048), dim3(256), 0, stream>>>(x, dd, n1w, n1b, xg, xb);
  attn_kernel<<<dim3(4096), dim3(256), 0, stream>>>(xg, Wqkvf, bqkv, biasmat, aout);
  proj_kernel<<<dim3(1024), dim3(256), 0, stream>>>(aout, Wprojf, pb, xb, n2w, n2b, xv, xn2);
  mlp_kernel<<<dim3(512), dim3(512), 0, stream>>>(xn2, xv, Wfc1f, f1b, Wfc2f, f2b, out);
}